// Round 1
// baseline (766.015 us; speedup 1.0000x reference)
//
#include <hip/hip_runtime.h>
#include <stdint.h>

#define NB 8192      // tokens
#define ND 2048      // input dim
#define NO 2048      // output dim
#define NE 8         // experts

typedef __bf16 bf16x8 __attribute__((ext_vector_type(8)));
typedef float floatx4 __attribute__((ext_vector_type(4)));

__device__ __forceinline__ unsigned short f2bf(float f) {
    union { float f; uint32_t u; } v; v.f = f;
    uint32_t u = v.u;
    return (unsigned short)((u + 0x7FFFu + ((u >> 16) & 1u)) >> 16);  // RNE
}

__global__ __launch_bounds__(256) void cvt_bf16_kernel(const float* __restrict__ in,
                                                       unsigned short* __restrict__ out, int n4) {
    int i = blockIdx.x * blockDim.x + threadIdx.x;
    int stride = gridDim.x * blockDim.x;
    for (; i < n4; i += stride) {
        float4 v = ((const float4*)in)[i];
        ushort4 o;
        o.x = f2bf(v.x); o.y = f2bf(v.y); o.z = f2bf(v.z); o.w = f2bf(v.w);
        ((ushort4*)out)[i] = o;
    }
}

// One wave per token: fp32 logits, top-2, softmax, atomic-append to expert lists.
__global__ __launch_bounds__(256) void router_kernel(const float* __restrict__ x,
        const float* __restrict__ rw, const float* __restrict__ rb,
        int* __restrict__ cnt, int* __restrict__ listTok, float* __restrict__ listW) {
    const int wave = threadIdx.x >> 6;
    const int lane = threadIdx.x & 63;
    const int t = blockIdx.x * 4 + wave;
    const float4* xp = (const float4*)(x + (size_t)t * ND);
    const float4* rp = (const float4*)rw;
    float acc[NE];
#pragma unroll
    for (int e = 0; e < NE; e++) acc[e] = 0.f;
#pragma unroll
    for (int i = 0; i < ND / 256; i++) {   // 8 iters: 64 lanes x float4
        int idx = i * 64 + lane;
        float4 xv = xp[idx];
#pragma unroll
        for (int e = 0; e < NE; e++) {
            float4 rv = rp[(size_t)e * (ND / 4) + idx];
            acc[e] += xv.x * rv.x + xv.y * rv.y + xv.z * rv.z + xv.w * rv.w;
        }
    }
#pragma unroll
    for (int e = 0; e < NE; e++) {
        float v = acc[e];
#pragma unroll
        for (int s = 32; s > 0; s >>= 1) v += __shfl_xor(v, s, 64);
        acc[e] = v;
    }
    if (lane == 0) {
        float lg[NE];
#pragma unroll
        for (int e = 0; e < NE; e++) lg[e] = acc[e] + rb[e];
        int i0 = 0; float v0 = lg[0];
#pragma unroll
        for (int e = 1; e < NE; e++) if (lg[e] > v0) { v0 = lg[e]; i0 = e; }  // first-max on ties (matches top_k)
        int i1 = -1; float v1 = -3.4e38f;
#pragma unroll
        for (int e = 0; e < NE; e++) if (e != i0 && lg[e] > v1) { v1 = lg[e]; i1 = e; }
        float ex = expf(v1 - v0);
        float w0 = 1.f / (1.f + ex);
        float w1 = ex / (1.f + ex);
        int p0 = atomicAdd(&cnt[i0], 1);
        listTok[i0 * NB + p0] = t; listW[i0 * NB + p0] = w0;
        int p1 = atomicAdd(&cnt[i1], 1);
        listTok[i1 * NB + p1] = t; listW[i1 * NB + p1] = w1;
    }
}

#define GLL16(g, l) __builtin_amdgcn_global_load_lds( \
    (const __attribute__((address_space(1))) void*)(g), \
    (__attribute__((address_space(3))) void*)(l), 16, 0, 0)

// Gathered 128x128 tile GEMM per expert (m97 structure), bf16 MFMA 16x16x32.
// C[m,n] = sum_k X[tok[m],k] * W_e[n,k]; epilogue: atomicAdd(out[tok[m],n], w[m]*(C+bias))
__global__ __launch_bounds__(256) void moe_gemm_kernel(
        const unsigned short* __restrict__ xbf, const unsigned short* __restrict__ wbf,
        const float* __restrict__ eb, const int* __restrict__ cntArr,
        const int* __restrict__ listTok, const float* __restrict__ listW,
        float* __restrict__ out) {
    __shared__ unsigned short sA[128 * 32];
    __shared__ unsigned short sB[128 * 32];
    __shared__ int sTok[128];
    __shared__ float sW[128];

    const int e = blockIdx.z, mt = blockIdx.y, nt = blockIdx.x;
    const int cnt = cntArr[e];
    if (mt * 128 >= cnt) return;
    const int tid = threadIdx.x;
    if (tid < 128) {
        int r = mt * 128 + tid;
        bool ok = r < cnt;
        sTok[tid] = ok ? listTok[e * NB + r] : 0;   // row 0 as safe dummy; masked at store
        sW[tid]   = ok ? listW[e * NB + r] : 0.f;
    }
    __syncthreads();

    // staging: 512 chunks of 16B per tile (128 rows x 64B), 2 chunks/thread/tile
    const char* gA[2]; const char* gB[2];
    unsigned short* lA[2]; unsigned short* lB[2];
#pragma unroll
    for (int r = 0; r < 2; r++) {
        int c = r * 256 + tid;
        int row = c >> 2, colb = (c & 3) * 16;
        gA[r] = (const char*)xbf + (size_t)sTok[row] * (ND * 2) + colb;
        gB[r] = (const char*)wbf + ((size_t)e * NO + (size_t)nt * 128 + row) * (ND * 2) + colb;
        lA[r] = sA + c * 8;
        lB[r] = sB + c * 8;
    }

    const int wave = tid >> 6, lane = tid & 63;
    const int wm = (wave >> 1) * 64, wn = (wave & 1) * 64;   // 2x2 wave grid, 64x64 each
    const int lr = lane & 15, lq = lane >> 4;

    floatx4 acc[4][4];
#pragma unroll
    for (int mi = 0; mi < 4; mi++)
#pragma unroll
        for (int nj = 0; nj < 4; nj++) acc[mi][nj] = (floatx4){0.f, 0.f, 0.f, 0.f};

    for (int kk = 0; kk < ND / 32; kk++) {
#pragma unroll
        for (int r = 0; r < 2; r++) {
            GLL16(gA[r], lA[r]);
            GLL16(gB[r], lB[r]);
            gA[r] += 64; gB[r] += 64;   // advance K by 32 bf16
        }
        __syncthreads();
        bf16x8 af[4], bfr[4];
#pragma unroll
        for (int mi = 0; mi < 4; mi++)
            af[mi] = *(const bf16x8*)&sA[(wm + mi * 16 + lr) * 32 + lq * 8];
#pragma unroll
        for (int nj = 0; nj < 4; nj++)
            bfr[nj] = *(const bf16x8*)&sB[(wn + nj * 16 + lr) * 32 + lq * 8];
#pragma unroll
        for (int mi = 0; mi < 4; mi++)
#pragma unroll
            for (int nj = 0; nj < 4; nj++)
                acc[mi][nj] = __builtin_amdgcn_mfma_f32_16x16x32_bf16(af[mi], bfr[nj], acc[mi][nj], 0, 0, 0);
        __syncthreads();
    }

    // epilogue: C/D layout col=lane&15, row=(lane>>4)*4+reg
#pragma unroll
    for (int nj = 0; nj < 4; nj++) {
        int gn = nt * 128 + wn + nj * 16 + lr;
        float bias = eb[(size_t)e * NO + gn];
#pragma unroll
        for (int mi = 0; mi < 4; mi++) {
#pragma unroll
            for (int r = 0; r < 4; r++) {
                int m = wm + mi * 16 + lq * 4 + r;
                if (mt * 128 + m < cnt) {
                    atomicAdd(out + (size_t)sTok[m] * NO + gn, sW[m] * (acc[mi][nj][r] + bias));
                }
            }
        }
    }
}

extern "C" void kernel_launch(void* const* d_in, const int* in_sizes, int n_in,
                              void* d_out, int out_size, void* d_ws, size_t ws_size,
                              hipStream_t stream) {
    const float* x        = (const float*)d_in[0];
    const float* router_w = (const float*)d_in[1];
    const float* router_b = (const float*)d_in[2];
    const float* expert_w = (const float*)d_in[3];
    const float* expert_b = (const float*)d_in[4];
    float* out = (float*)d_out;
    char* ws = (char*)d_ws;

    unsigned short* xbf = (unsigned short*)ws;                 // 33,554,432 B
    unsigned short* wbf = (unsigned short*)(ws + 33554432);    // 67,108,864 B
    int*   cnt     = (int*)(ws + 100663296);                   // 128 B (8 used)
    int*   listTok = (int*)(ws + 100663424);                   // 262,144 B
    float* listW   = (float*)(ws + 100925568);                 // 262,144 B
    // total ws use: ~96.5 MB

    hipMemsetAsync(cnt, 0, 128, stream);
    hipMemsetAsync(out, 0, (size_t)out_size * sizeof(float), stream);
    cvt_bf16_kernel<<<NB * ND / 4 / 256, 256, 0, stream>>>(x, xbf, NB * ND / 4);
    cvt_bf16_kernel<<<NE * NO * ND / 4 / 256, 256, 0, stream>>>(expert_w, wbf, NE * NO * ND / 4);
    router_kernel<<<NB / 4, 256, 0, stream>>>(x, router_w, router_b, cnt, listTok, listW);
    moe_gemm_kernel<<<dim3(NO / 128, NB / 128, NE), 256, 0, stream>>>(
        xbf, wbf, expert_b, cnt, listTok, listW, out);
}

// Round 2
// 624.861 us; speedup vs baseline: 1.2259x; 1.2259x over previous
//
#include <hip/hip_runtime.h>
#include <stdint.h>

#define NB 8192      // tokens
#define ND 2048      // input dim
#define NO 2048      // output dim
#define NE 8         // experts

typedef __bf16 bf16x8 __attribute__((ext_vector_type(8)));
typedef float floatx4 __attribute__((ext_vector_type(4)));

__device__ __forceinline__ unsigned short f2bf(float f) {
    union { float f; uint32_t u; } v; v.f = f;
    uint32_t u = v.u;
    return (unsigned short)((u + 0x7FFFu + ((u >> 16) & 1u)) >> 16);  // RNE
}

__global__ __launch_bounds__(256) void cvt_bf16_kernel(const float* __restrict__ in,
                                                       unsigned short* __restrict__ out, int n4) {
    int i = blockIdx.x * blockDim.x + threadIdx.x;
    int stride = gridDim.x * blockDim.x;
    for (; i < n4; i += stride) {
        float4 v = ((const float4*)in)[i];
        ushort4 o;
        o.x = f2bf(v.x); o.y = f2bf(v.y); o.z = f2bf(v.z); o.w = f2bf(v.w);
        ((ushort4*)out)[i] = o;
    }
}

// Phase 1: one wave per token, fp32 logits, top-2 + softmax. NO atomics.
__global__ __launch_bounds__(256) void router_topk_kernel(const float* __restrict__ x,
        const float* __restrict__ rw, const float* __restrict__ rb,
        int* __restrict__ i0a, int* __restrict__ i1a,
        float* __restrict__ w0a, float* __restrict__ w1a) {
    const int wave = threadIdx.x >> 6;
    const int lane = threadIdx.x & 63;
    const int t = blockIdx.x * 4 + wave;
    const float4* xp = (const float4*)(x + (size_t)t * ND);
    const float4* rp = (const float4*)rw;
    float acc[NE];
#pragma unroll
    for (int e = 0; e < NE; e++) acc[e] = 0.f;
#pragma unroll
    for (int i = 0; i < ND / 256; i++) {   // 8 iters: 64 lanes x float4
        int idx = i * 64 + lane;
        float4 xv = xp[idx];
#pragma unroll
        for (int e = 0; e < NE; e++) {
            float4 rv = rp[(size_t)e * (ND / 4) + idx];
            acc[e] += xv.x * rv.x + xv.y * rv.y + xv.z * rv.z + xv.w * rv.w;
        }
    }
#pragma unroll
    for (int e = 0; e < NE; e++) {
        float v = acc[e];
#pragma unroll
        for (int s = 32; s > 0; s >>= 1) v += __shfl_xor(v, s, 64);
        acc[e] = v;
    }
    if (lane == 0) {
        float lg[NE];
#pragma unroll
        for (int e = 0; e < NE; e++) lg[e] = acc[e] + rb[e];
        int i0 = 0; float v0 = lg[0];
#pragma unroll
        for (int e = 1; e < NE; e++) if (lg[e] > v0) { v0 = lg[e]; i0 = e; }  // first-max ties = top_k
        int i1 = -1; float v1 = -3.4e38f;
#pragma unroll
        for (int e = 0; e < NE; e++) if (e != i0 && lg[e] > v1) { v1 = lg[e]; i1 = e; }
        float ex = expf(v1 - v0);
        float inv = 1.f / (1.f + ex);
        i0a[t] = i0; i1a[t] = i1;
        w0a[t] = inv; w1a[t] = ex * inv;
    }
}

// Phase 2: one block per expert; ballot-scan compaction of primary + secondary lists.
__global__ __launch_bounds__(256) void build_lists_kernel(
        const int* __restrict__ i0a, const int* __restrict__ i1a,
        const float* __restrict__ w0a, const float* __restrict__ w1a,
        int* __restrict__ cntA, int* __restrict__ cntB,
        int* __restrict__ tokA, float* __restrict__ wA,
        int* __restrict__ tokB, float* __restrict__ wB) {
    const int e = blockIdx.x;
    const int tid = threadIdx.x, wave = tid >> 6, lane = tid & 63;
    __shared__ int waveSum[4];

#pragma unroll
    for (int which = 0; which < 2; which++) {
        const int* sel = which ? i1a : i0a;
        const float* wsel = which ? w1a : w0a;
        int* tok = which ? tokB : tokA;
        float* wl = which ? wB : wA;
        int base = 0;
        for (int it = 0; it < NB; it += 256) {
            int t = it + tid;
            bool f = (sel[t] == e);
            unsigned long long mask = __ballot(f);
            int slot = __popcll(mask & ((1ull << lane) - 1ull));
            if (lane == 0) waveSum[wave] = __popcll(mask);
            __syncthreads();
            int wbase = base;
            for (int w = 0; w < wave; w++) wbase += waveSum[w];
            if (f) { tok[e * NB + wbase + slot] = t; wl[e * NB + wbase + slot] = wsel[t]; }
            base += waveSum[0] + waveSum[1] + waveSum[2] + waveSum[3];
            __syncthreads();
        }
        if (tid == 0) { if (which) cntB[e] = base; else cntA[e] = base; }
    }
}

#define GLL16(g, l) __builtin_amdgcn_global_load_lds( \
    (const __attribute__((address_space(1))) void*)(g), \
    (__attribute__((address_space(3))) void*)(l), 16, 0, 0)

// Gathered 128x128 tile GEMM per expert (m97 structure), bf16 MFMA 16x16x32.
// C[m,n] = sum_k X[tok[m],k] * W_e[n,k]
// ACCUM=false: out[tok[m],n]  = w[m]*(C+bias)        (rows disjoint: plain store)
// ACCUM=true : out[tok[m],n] += w[m]*(C+bias)        (rows disjoint within pass: load+store)
template <bool ACCUM>
__global__ __launch_bounds__(256) void moe_gemm_kernel(
        const unsigned short* __restrict__ xbf, const unsigned short* __restrict__ wbf,
        const float* __restrict__ eb, const int* __restrict__ cntArr,
        const int* __restrict__ listTok, const float* __restrict__ listW,
        float* __restrict__ out) {
    __shared__ unsigned short sA[128 * 32];
    __shared__ unsigned short sB[128 * 32];
    __shared__ int sTok[128];
    __shared__ float sW[128];

    const int e = blockIdx.z, mt = blockIdx.y, nt = blockIdx.x;
    const int cnt = cntArr[e];
    if (mt * 128 >= cnt) return;
    const int tid = threadIdx.x;
    if (tid < 128) {
        int r = mt * 128 + tid;
        bool ok = r < cnt;
        sTok[tid] = ok ? listTok[e * NB + r] : 0;   // row 0 as safe dummy; masked at store
        sW[tid]   = ok ? listW[e * NB + r] : 0.f;
    }
    __syncthreads();

    // staging: 512 chunks of 16B per tile (128 rows x 64B), 2 chunks/thread/tile
    const char* gA[2]; const char* gB[2];
    unsigned short* lA[2]; unsigned short* lB[2];
#pragma unroll
    for (int r = 0; r < 2; r++) {
        int c = r * 256 + tid;
        int row = c >> 2, colb = (c & 3) * 16;
        gA[r] = (const char*)xbf + (size_t)sTok[row] * (ND * 2) + colb;
        gB[r] = (const char*)wbf + ((size_t)e * NO + (size_t)nt * 128 + row) * (ND * 2) + colb;
        lA[r] = sA + c * 8;
        lB[r] = sB + c * 8;
    }

    const int wave = tid >> 6, lane = tid & 63;
    const int wm = (wave >> 1) * 64, wn = (wave & 1) * 64;   // 2x2 wave grid, 64x64 each
    const int lr = lane & 15, lq = lane >> 4;

    floatx4 acc[4][4];
#pragma unroll
    for (int mi = 0; mi < 4; mi++)
#pragma unroll
        for (int nj = 0; nj < 4; nj++) acc[mi][nj] = (floatx4){0.f, 0.f, 0.f, 0.f};

    for (int kk = 0; kk < ND / 32; kk++) {
#pragma unroll
        for (int r = 0; r < 2; r++) {
            GLL16(gA[r], lA[r]);
            GLL16(gB[r], lB[r]);
            gA[r] += 64; gB[r] += 64;   // advance K by 32 bf16
        }
        __syncthreads();
        bf16x8 af[4], bfr[4];
#pragma unroll
        for (int mi = 0; mi < 4; mi++)
            af[mi] = *(const bf16x8*)&sA[(wm + mi * 16 + lr) * 32 + lq * 8];
#pragma unroll
        for (int nj = 0; nj < 4; nj++)
            bfr[nj] = *(const bf16x8*)&sB[(wn + nj * 16 + lr) * 32 + lq * 8];
#pragma unroll
        for (int mi = 0; mi < 4; mi++)
#pragma unroll
            for (int nj = 0; nj < 4; nj++)
                acc[mi][nj] = __builtin_amdgcn_mfma_f32_16x16x32_bf16(af[mi], bfr[nj], acc[mi][nj], 0, 0, 0);
        __syncthreads();
    }

    // epilogue: C/D layout col=lane&15, row=(lane>>4)*4+reg — non-atomic
#pragma unroll
    for (int nj = 0; nj < 4; nj++) {
        int gn = nt * 128 + wn + nj * 16 + lr;
        float bias = eb[(size_t)e * NO + gn];
#pragma unroll
        for (int mi = 0; mi < 4; mi++) {
#pragma unroll
            for (int r = 0; r < 4; r++) {
                int m = wm + mi * 16 + lq * 4 + r;
                if (mt * 128 + m < cnt) {
                    float* p = out + (size_t)sTok[m] * NO + gn;
                    float v = sW[m] * (acc[mi][nj][r] + bias);
                    if (ACCUM) v += *p;
                    *p = v;
                }
            }
        }
    }
}

extern "C" void kernel_launch(void* const* d_in, const int* in_sizes, int n_in,
                              void* d_out, int out_size, void* d_ws, size_t ws_size,
                              hipStream_t stream) {
    const float* x        = (const float*)d_in[0];
    const float* router_w = (const float*)d_in[1];
    const float* router_b = (const float*)d_in[2];
    const float* expert_w = (const float*)d_in[3];
    const float* expert_b = (const float*)d_in[4];
    float* out = (float*)d_out;
    char* ws = (char*)d_ws;

    unsigned short* xbf = (unsigned short*)ws;                 // 33,554,432 B
    unsigned short* wbf = (unsigned short*)(ws + 33554432);    // 67,108,864 B -> ends 100,663,296
    size_t o = 100663296;
    int*   tokA = (int*)(ws + o);   o += NE * NB * 4;          // 256 KB
    float* wA   = (float*)(ws + o); o += NE * NB * 4;
    int*   tokB = (int*)(ws + o);   o += NE * NB * 4;
    float* wB   = (float*)(ws + o); o += NE * NB * 4;
    int*   i0a  = (int*)(ws + o);   o += NB * 4;
    int*   i1a  = (int*)(ws + o);   o += NB * 4;
    float* w0a  = (float*)(ws + o); o += NB * 4;
    float* w1a  = (float*)(ws + o); o += NB * 4;
    int*   cntA = (int*)(ws + o);   o += 128;
    int*   cntB = (int*)(ws + o);   o += 128;
    // total ws use: ~98 MB

    cvt_bf16_kernel<<<NB * ND / 4 / 256, 256, 0, stream>>>(x, xbf, NB * ND / 4);
    cvt_bf16_kernel<<<NE * NO * ND / 4 / 256, 256, 0, stream>>>(expert_w, wbf, NE * NO * ND / 4);
    router_topk_kernel<<<NB / 4, 256, 0, stream>>>(x, router_w, router_b, i0a, i1a, w0a, w1a);
    build_lists_kernel<<<NE, 256, 0, stream>>>(i0a, i1a, w0a, w1a, cntA, cntB, tokA, wA, tokB, wB);
    moe_gemm_kernel<false><<<dim3(NO / 128, NB / 128, NE), 256, 0, stream>>>(
        xbf, wbf, expert_b, cntA, tokA, wA, out);
    moe_gemm_kernel<true><<<dim3(NO / 128, NB / 128, NE), 256, 0, stream>>>(
        xbf, wbf, expert_b, cntB, tokB, wB, out);
}

// Round 3
// 604.250 us; speedup vs baseline: 1.2677x; 1.0341x over previous
//
#include <hip/hip_runtime.h>
#include <stdint.h>

#define NB 8192      // tokens
#define ND 2048      // input dim
#define NO 2048      // output dim
#define NE 8         // experts

typedef __bf16 bf16x8 __attribute__((ext_vector_type(8)));
typedef float floatx4 __attribute__((ext_vector_type(4)));

__device__ __forceinline__ unsigned short f2bf(float f) {
    union { float f; uint32_t u; } v; v.f = f;
    uint32_t u = v.u;
    return (unsigned short)((u + 0x7FFFu + ((u >> 16) & 1u)) >> 16);  // RNE
}

// Convert both fp32 arrays (x, expert_w) to bf16 in one launch.
__global__ __launch_bounds__(256) void cvt2_bf16_kernel(
        const float* __restrict__ a, unsigned short* __restrict__ oa, int na4,
        const float* __restrict__ b, unsigned short* __restrict__ ob, int nb4) {
    int i = blockIdx.x * blockDim.x + threadIdx.x;
    int stride = gridDim.x * blockDim.x;
    int tot = na4 + nb4;
    for (; i < tot; i += stride) {
        const float4* src = (i < na4) ? (const float4*)a : (const float4*)b;
        ushort4* dst = (i < na4) ? (ushort4*)oa : (ushort4*)ob;
        int j = (i < na4) ? i : i - na4;
        float4 v = src[j];
        ushort4 o;
        o.x = f2bf(v.x); o.y = f2bf(v.y); o.z = f2bf(v.z); o.w = f2bf(v.w);
        dst[j] = o;
    }
}

// Phase 1: one wave per token, fp32 logits, top-2 + softmax. NO atomics.
__global__ __launch_bounds__(256) void router_topk_kernel(const float* __restrict__ x,
        const float* __restrict__ rw, const float* __restrict__ rb,
        int* __restrict__ i0a, int* __restrict__ i1a,
        float* __restrict__ w0a, float* __restrict__ w1a) {
    const int wave = threadIdx.x >> 6;
    const int lane = threadIdx.x & 63;
    const int t = blockIdx.x * 4 + wave;
    const float4* xp = (const float4*)(x + (size_t)t * ND);
    const float4* rp = (const float4*)rw;
    float acc[NE];
#pragma unroll
    for (int e = 0; e < NE; e++) acc[e] = 0.f;
#pragma unroll
    for (int i = 0; i < ND / 256; i++) {   // 8 iters: 64 lanes x float4
        int idx = i * 64 + lane;
        float4 xv = xp[idx];
#pragma unroll
        for (int e = 0; e < NE; e++) {
            float4 rv = rp[(size_t)e * (ND / 4) + idx];
            acc[e] += xv.x * rv.x + xv.y * rv.y + xv.z * rv.z + xv.w * rv.w;
        }
    }
#pragma unroll
    for (int e = 0; e < NE; e++) {
        float v = acc[e];
#pragma unroll
        for (int s = 32; s > 0; s >>= 1) v += __shfl_xor(v, s, 64);
        acc[e] = v;
    }
    if (lane == 0) {
        float lg[NE];
#pragma unroll
        for (int e = 0; e < NE; e++) lg[e] = acc[e] + rb[e];
        int i0 = 0; float v0 = lg[0];
#pragma unroll
        for (int e = 1; e < NE; e++) if (lg[e] > v0) { v0 = lg[e]; i0 = e; }  // first-max ties = top_k
        int i1 = -1; float v1 = -3.4e38f;
#pragma unroll
        for (int e = 0; e < NE; e++) if (e != i0 && lg[e] > v1) { v1 = lg[e]; i1 = e; }
        float ex = expf(v1 - v0);
        float inv = 1.f / (1.f + ex);
        i0a[t] = i0; i1a[t] = i1;
        w0a[t] = inv; w1a[t] = ex * inv;
    }
}

// Phase 2: parallel ballot-compaction. One wave handles 64 tokens; per-expert
// ballots, one atomicAdd per (wave, expert) to reserve list space, scatter.
// List order is arbitrary — the gemm doesn't care.
__global__ __launch_bounds__(256) void compact_kernel(
        const int* __restrict__ i0a, const int* __restrict__ i1a,
        const float* __restrict__ w0a, const float* __restrict__ w1a,
        int* __restrict__ cntA, int* __restrict__ cntB,
        int* __restrict__ tokA, float* __restrict__ wA,
        int* __restrict__ tokB, float* __restrict__ wB) {
    const int lane = threadIdx.x & 63;
    const int gw = (blockIdx.x * 256 + threadIdx.x) >> 6;   // 0..127
    const int t = gw * 64 + lane;
#pragma unroll
    for (int which = 0; which < 2; which++) {
        int sel   = which ? i1a[t] : i0a[t];
        float w   = which ? w1a[t] : w0a[t];
        int* cnt  = which ? cntB : cntA;
        int* tok  = which ? tokB : tokA;
        float* wl = which ? wB : wA;
        unsigned long long m[NE];
#pragma unroll
        for (int e = 0; e < NE; e++) m[e] = __ballot(sel == e);
        int slot = __popcll(m[sel] & ((1ull << lane) - 1ull));
        int base = 0;
        if (lane < NE) base = atomicAdd(&cnt[lane], (int)__popcll(m[lane]));
        base = __shfl(base, sel, 64);
        tok[sel * NB + base + slot] = t;
        wl[sel * NB + base + slot]  = w;
    }
}

#define GLL16(g, l) __builtin_amdgcn_global_load_lds( \
    (const __attribute__((address_space(1))) void*)(g), \
    (__attribute__((address_space(3))) void*)(l), 16, 0, 0)

// Gathered 128x128 tile GEMM per expert (m97 structure), bf16 MFMA 16x16x32.
// C[m,n] = sum_k X[tok[m],k] * W_e[n,k]
// ACCUM=false: out[tok[m],n]  = w[m]*(C+bias)   (rows disjoint: plain store)
// ACCUM=true : out[tok[m],n] += w[m]*(C+bias)   (rows disjoint within pass)
template <bool ACCUM>
__global__ __launch_bounds__(256, 4) void moe_gemm_kernel(
        const unsigned short* __restrict__ xbf, const unsigned short* __restrict__ wbf,
        const float* __restrict__ eb, const int* __restrict__ cntArr,
        const int* __restrict__ listTok, const float* __restrict__ listW,
        float* __restrict__ out) {
    __shared__ unsigned short sA[128 * 32];
    __shared__ unsigned short sB[128 * 32];
    __shared__ int sTok[128];
    __shared__ float sW[128];

    const int e = blockIdx.z, mt = blockIdx.y, nt = blockIdx.x;
    const int cnt = cntArr[e];
    if (mt * 128 >= cnt) return;
    const int tid = threadIdx.x;
    if (tid < 128) {
        int r = mt * 128 + tid;
        bool ok = r < cnt;
        sTok[tid] = ok ? listTok[e * NB + r] : 0;   // row 0 as safe dummy; masked at store
        sW[tid]   = ok ? listW[e * NB + r] : 0.f;
    }
    __syncthreads();

    // staging: 512 chunks of 16B per tile (128 rows x 64B), 2 chunks/thread/tile
    const char* gA[2]; const char* gB[2];
    unsigned short* lA[2]; unsigned short* lB[2];
#pragma unroll
    for (int r = 0; r < 2; r++) {
        int c = r * 256 + tid;
        int row = c >> 2, colb = (c & 3) * 16;
        gA[r] = (const char*)xbf + (size_t)sTok[row] * (ND * 2) + colb;
        gB[r] = (const char*)wbf + ((size_t)e * NO + (size_t)nt * 128 + row) * (ND * 2) + colb;
        lA[r] = sA + c * 8;
        lB[r] = sB + c * 8;
    }

    const int wave = tid >> 6, lane = tid & 63;
    const int wm = (wave >> 1) * 64, wn = (wave & 1) * 64;   // 2x2 wave grid, 64x64 each
    const int lr = lane & 15, lq = lane >> 4;

    floatx4 acc[4][4];
#pragma unroll
    for (int mi = 0; mi < 4; mi++)
#pragma unroll
        for (int nj = 0; nj < 4; nj++) acc[mi][nj] = (floatx4){0.f, 0.f, 0.f, 0.f};

    for (int kk = 0; kk < ND / 32; kk++) {
#pragma unroll
        for (int r = 0; r < 2; r++) {
            GLL16(gA[r], lA[r]);
            GLL16(gB[r], lB[r]);
            gA[r] += 64; gB[r] += 64;   // advance K by 32 bf16
        }
        __syncthreads();
        bf16x8 af[4], bfr[4];
#pragma unroll
        for (int mi = 0; mi < 4; mi++)
            af[mi] = *(const bf16x8*)&sA[(wm + mi * 16 + lr) * 32 + lq * 8];
#pragma unroll
        for (int nj = 0; nj < 4; nj++)
            bfr[nj] = *(const bf16x8*)&sB[(wn + nj * 16 + lr) * 32 + lq * 8];
#pragma unroll
        for (int mi = 0; mi < 4; mi++)
#pragma unroll
            for (int nj = 0; nj < 4; nj++)
                acc[mi][nj] = __builtin_amdgcn_mfma_f32_16x16x32_bf16(af[mi], bfr[nj], acc[mi][nj], 0, 0, 0);
        __syncthreads();
    }

    // epilogue: C/D layout col=lane&15, row=(lane>>4)*4+reg — non-atomic
#pragma unroll
    for (int nj = 0; nj < 4; nj++) {
        int gn = nt * 128 + wn + nj * 16 + lr;
        float bias = eb[(size_t)e * NO + gn];
#pragma unroll
        for (int mi = 0; mi < 4; mi++) {
#pragma unroll
            for (int r = 0; r < 4; r++) {
                int m = wm + mi * 16 + lq * 4 + r;
                if (mt * 128 + m < cnt) {
                    float* p = out + (size_t)sTok[m] * NO + gn;
                    float v = sW[m] * (acc[mi][nj][r] + bias);
                    if (ACCUM) v += *p;
                    *p = v;
                }
            }
        }
    }
}

extern "C" void kernel_launch(void* const* d_in, const int* in_sizes, int n_in,
                              void* d_out, int out_size, void* d_ws, size_t ws_size,
                              hipStream_t stream) {
    const float* x        = (const float*)d_in[0];
    const float* router_w = (const float*)d_in[1];
    const float* router_b = (const float*)d_in[2];
    const float* expert_w = (const float*)d_in[3];
    const float* expert_b = (const float*)d_in[4];
    float* out = (float*)d_out;
    char* ws = (char*)d_ws;

    unsigned short* xbf = (unsigned short*)ws;                 // 33,554,432 B
    unsigned short* wbf = (unsigned short*)(ws + 33554432);    // 67,108,864 B -> ends 100,663,296
    size_t o = 100663296;
    int*   tokA = (int*)(ws + o);   o += NE * NB * 4;          // 256 KB
    float* wA   = (float*)(ws + o); o += NE * NB * 4;
    int*   tokB = (int*)(ws + o);   o += NE * NB * 4;
    float* wB   = (float*)(ws + o); o += NE * NB * 4;
    int*   i0a  = (int*)(ws + o);   o += NB * 4;
    int*   i1a  = (int*)(ws + o);   o += NB * 4;
    float* w0a  = (float*)(ws + o); o += NB * 4;
    float* w1a  = (float*)(ws + o); o += NB * 4;
    int*   cntA = (int*)(ws + o);   o += 128;
    int*   cntB = (int*)(ws + o);   o += 128;
    // total ws use: ~98 MB

    hipMemsetAsync(cntA, 0, 256, stream);   // cntA + cntB (contiguous)
    cvt2_bf16_kernel<<<2048, 256, 0, stream>>>(x, xbf, NB * ND / 4,
                                               expert_w, wbf, NE * NO * ND / 4);
    router_topk_kernel<<<NB / 4, 256, 0, stream>>>(x, router_w, router_b, i0a, i1a, w0a, w1a);
    compact_kernel<<<NB / 64 / 4, 256, 0, stream>>>(i0a, i1a, w0a, w1a,
                                                    cntA, cntB, tokA, wA, tokB, wB);
    moe_gemm_kernel<false><<<dim3(NO / 128, NB / 128, NE), 256, 0, stream>>>(
        xbf, wbf, expert_b, cntA, tokA, wA, out);
    moe_gemm_kernel<true><<<dim3(NO / 128, NB / 128, NE), 256, 0, stream>>>(
        xbf, wbf, expert_b, cntB, tokB, wB, out);
}